// Round 13
// baseline (192.588 us; speedup 1.0000x reference)
//
#include <hip/hip_runtime.h>
#include <stdint.h>

// Fixed 8x8x8 grid complex: nV=512, nE=2863, nT=4410, nTet=2058, nS=9843.
// Dim-1 pairs via COHOMOLOGY (coboundary delta_1) + clearing of MST edges:
// rows = edges (reverse filtration order), bits = triangles (reverse order).
// Negative (MST) edges' rows would reduce to zero -> cleared upfront.
#define MAX_E 3072
#define MAX_T 4608
#define MAX_V 1024
#define TW    72     // u64 words per row >= ceil(nT/64); 2 words/lane, lanes 0..35
#define INF_I 0x7fffffff
#define RB_E  12     // edge-rank blocks
#define RB_T  18     // tri-rank blocks
#define RB_C  24     // clear blocks
// spiv packing: value = (row << 14) | epoch. atomicMin orders by row (high
// bits); epoch==current pass marks "claimed this pass, row may be mid-write".
#define EP_BITS  14
#define EP_MASK  0x3FFF
#define EP_DONE  0x3FFF   // settled marker (pass counter capped below it)

typedef unsigned long long ull;

__device__ int   g_erank[MAX_E];             // edge local idx -> rank (f desc, idx asc)
__device__ int   g_eorder[MAX_E];            // rank -> edge local idx
__device__ float g_ef[MAX_E];                // f by edge rank
__device__ int   g_trank[MAX_T];             // tri local idx -> rank
__device__ float g_tf[MAX_T];                // f by tri rank
__device__ __attribute__((aligned(16))) ull g_rows[(size_t)MAX_E * TW];
__device__ int   g_mst[MAX_E];               // edge idx -> 1 if MST (negative) edge
__device__ float g_loss0;

// sd is sorted (verts, edges, tris, tets): first index with dim > d.
__device__ __forceinline__ int ub_dim(const int* __restrict__ sd, int nS, int d) {
  int lo = 0, hi = nS;
  while (lo < hi) { int mid = (lo + hi) >> 1; if (sd[mid] <= d) lo = mid + 1; else hi = mid; }
  return lo;
}

// Orderable key: key_j > key_i  <=>  (fj > fi) || (fj == fi && j < i).
__device__ __forceinline__ ull rank_key(float f, int j) {
  unsigned bb = __float_as_uint(f);
  unsigned ord = (bb & 0x80000000u) ? ~bb : (bb | 0x80000000u);
  return ((ull)ord << 32) | (ull)(0xffffffffu - (unsigned)j);
}

// Count keys > ki with 4 independent ds_read_b128 in flight per iteration
// (ILP hides LDS latency: rank blocks run 1 wave/SIMD, no TLP available).
__device__ __forceinline__ int rank_count64(const ull* __restrict__ sk, int n, ull ki) {
  int r = 0, j = 0;
  for (; j + 8 <= n; j += 8) {
    ulonglong2 a = *(const ulonglong2*)(sk + j);
    ulonglong2 b = *(const ulonglong2*)(sk + j + 2);
    ulonglong2 c = *(const ulonglong2*)(sk + j + 4);
    ulonglong2 d = *(const ulonglong2*)(sk + j + 6);
    r += (int)(a.x > ki) + (int)(a.y > ki) + (int)(b.x > ki) + (int)(b.y > ki)
       + (int)(c.x > ki) + (int)(c.y > ki) + (int)(d.x > ki) + (int)(d.y > ki);
  }
  for (; j < n; ++j) r += (int)(sk[j] > ki);
  return r;
}

// Find with path halving. Races with concurrent halving writes are benign
// (every write installs an ancestor; hooks are barrier-separated from finds).
__device__ __forceinline__ int uf_find(int* par, int x) {
  for (;;) {
    int p = par[x];
    if (p == x) return x;
    int gp = par[p];
    if (p != gp) par[x] = gp;
    x = gp;
  }
}

// K1: independent roles — edge ranks | tri ranks | UF (Boruvka) | row clear.
// UF is rank-independent (writes g_mst by edge idx), so all roles overlap.
union SharedK1 {
  struct { alignas(16) ull sk[MAX_T]; } rank;
  struct {
    int par[MAX_V]; ull cand[MAX_V]; int hookTo[MAX_V];
    int eu[MAX_E], ev2[MAX_E];
    float efv[MAX_E];
    unsigned int ekey[MAX_E];
    unsigned short alive[2][MAX_E];
    unsigned char mstf[MAX_E];
  } uf;
};

__global__ void __launch_bounds__(256) k_main1(const float* __restrict__ beta,
                                               const int* __restrict__ sv,
                                               const int* __restrict__ sd,
                                               int nV, int nS) {
  __shared__ SharedK1 sh;
  __shared__ float aS[4], aM[4], aW[4];
  __shared__ int nNext;
  int b = blockIdx.x, tid = threadIdx.x;
  int nE = ub_dim(sd, nS, 1) - nV;

  if (b < RB_E) {
    // ---- edge ranks via u64-key counting ----
    int i = b * 256 + tid;
    float fi = 0.f;
    for (int j = tid; j < nE; j += 256) {     // j==i hit here (j ≡ tid mod 256)
      const int* p = &sv[(size_t)(nV + j) * 4];
      float fj = fminf(beta[p[0]], beta[p[1]]);
      if (j == i) fi = fj;
      sh.rank.sk[j] = rank_key(fj, j);
    }
    __syncthreads();
    if (i >= nE) return;
    int r = rank_count64(sh.rank.sk, nE, sh.rank.sk[i]);
    g_erank[i] = r;
    g_eorder[r] = i;
    g_ef[r] = fi;
    return;
  }
  if (b < RB_E + RB_T) {
    // ---- tri ranks ----
    int nT = ub_dim(sd, nS, 2) - nV - nE;
    int base = nV + nE;
    int i = (b - RB_E) * 256 + tid;
    float fi = 0.f;
    for (int j = tid; j < nT; j += 256) {
      const int* p = &sv[(size_t)(base + j) * 4];
      float fj = fminf(fminf(beta[p[0]], beta[p[1]]), beta[p[2]]);
      if (j == i) fi = fj;
      sh.rank.sk[j] = rank_key(fj, j);
    }
    __syncthreads();
    if (i >= nT) return;
    int r = rank_count64(sh.rank.sk, nT, sh.rank.sk[i]);
    g_trank[i] = r;
    g_tf[r] = fi;
    return;
  }
  if (b > RB_E + RB_T) {
    // ---- clear g_rows ----
    size_t i = (size_t)(b - RB_E - RB_T - 1) * 256 + tid;
    size_t stride = (size_t)RB_C * 256;
    for (size_t k = i; k < (size_t)MAX_E * TW; k += stride) g_rows[k] = 0ull;
    return;
  }

  // ---- UF role: loss0 = sum_v f(v) - max_v f(v) - W(canonical max ST).
  // Boruvka with STRICT keys (f desc, idx asc) == Kruskal's negative edge set.
  // Path-halving finds, 2 compress sweeps, terminate on empty alive list.
  int lane = tid & 63, wave = tid >> 6;
  int* par = sh.uf.par;
  for (int v = tid; v < nV; v += 256) par[v] = v;
  for (int e = tid; e < nE; e += 256) {
    int u = sv[(size_t)(nV + e) * 4];
    int v = sv[(size_t)(nV + e) * 4 + 1];
    sh.uf.eu[e] = u; sh.uf.ev2[e] = v;
    float fe = fminf(beta[u], beta[v]);
    sh.uf.efv[e] = fe;
    unsigned int bb = __float_as_uint(fe);
    sh.uf.ekey[e] = (bb & 0x80000000u) ? ~bb : (bb | 0x80000000u);  // orderable
    sh.uf.alive[0][e] = (unsigned short)e;
    sh.uf.mstf[e] = 0;
  }
  float s = 0.f, m = -3.0e38f;
  for (int v = tid; v < nV; v += 256) { float fv = beta[v]; s += fv; m = fmaxf(m, fv); }
  float W = 0.f;
  int nAlive = nE, cur = 0;
  __syncthreads();
  for (int phase = 0; phase < 20 && nAlive > 0; ++phase) {
    for (int v = tid; v < nV; v += 256) sh.uf.cand[v] = 0ull;
    if (tid == 0) nNext = 0;
    __syncthreads();
    for (int i0 = 0; i0 < nAlive; i0 += 256) {
      int i = i0 + tid;
      int e = -1;
      bool cross = false;
      int ra = 0, rb = 0;
      if (i < nAlive) {
        e = sh.uf.alive[cur][i];
        ra = uf_find(par, sh.uf.eu[e]);
        rb = uf_find(par, sh.uf.ev2[e]);
        cross = (ra != rb);
      }
      ull mb = __ballot(cross);
      int base = 0;
      if (lane == 0 && mb) base = atomicAdd(&nNext, __popcll(mb));
      base = __shfl(base, 0);
      if (cross) {
        int off = __popcll(mb & ((1ull << lane) - 1ull));
        sh.uf.alive[cur ^ 1][base + off] = (unsigned short)e;
        // key: larger f wins; tie -> SMALLER edge idx wins (canonical order)
        ull key = ((ull)sh.uf.ekey[e] << 32) | (ull)(0xffffffffu - (unsigned)e);
        atomicMax(&sh.uf.cand[ra], key);
        atomicMax(&sh.uf.cand[rb], key);
      }
    }
    __syncthreads();
    for (int v = tid; v < nV; v += 256) {
      int t = -1;
      ull cv = sh.uf.cand[v];
      if (par[v] == v && cv) {
        int e = (int)(0xffffffffu - (unsigned)(cv & 0xffffffffu));
        int ra = uf_find(par, sh.uf.eu[e]);
        int rb = uf_find(par, sh.uf.ev2[e]);
        int other = (ra == v) ? rb : ra;
        if (sh.uf.cand[other] != cv || v < other) t = other;  // break 2-cycles
      }
      sh.uf.hookTo[v] = t;
    }
    __syncthreads();
    for (int v = tid; v < nV; v += 256) {
      int t = sh.uf.hookTo[v];
      if (t >= 0) {
        par[v] = t;
        int e = (int)(0xffffffffu - (unsigned)(sh.uf.cand[v] & 0xffffffffu));
        W += sh.uf.efv[e];
        sh.uf.mstf[e] = 1;                   // negative edge
      }
    }
    __syncthreads();
    for (int it = 0; it < 2; ++it) {
      for (int v = tid; v < nV; v += 256) {
        int p = par[v]; int gp = par[p];
        if (p != gp) par[v] = gp;
      }
      __syncthreads();
    }
    nAlive = nNext;
    cur ^= 1;
    __syncthreads();                          // nNext read-before-reset fence
  }
  __syncthreads();
  // write MST flags once
  for (int e = tid; e < nE; e += 256) g_mst[e] = sh.uf.mstf[e];
  #pragma unroll
  for (int off = 32; off; off >>= 1) {
    s += __shfl_xor(s, off, 64);
    m = fmaxf(m, __shfl_xor(m, off, 64));
    W += __shfl_xor(W, off, 64);
  }
  if (lane == 0) { aS[wave] = s; aM[wave] = m; aW[wave] = W; }
  __syncthreads();
  if (tid == 0) {
    float S = 0.f, M = -3.0e38f, WW = 0.f;
    for (int i = 0; i < 4; ++i) { S += aS[i]; M = fmaxf(M, aM[i]); WW += aW[i]; }
    g_loss0 = S - M - WW;
  }
}

__device__ __forceinline__ int row_low(ull x, ull y, int lane) {
  ull msk = __ballot((x | y) != 0ull);
  int hb = y ? (lane * 128 + 127 - __clzll(y)) : (lane * 128 + 63 - __clzll(x | 1ull));
  return msk ? __shfl(hb, 63 - __clzll(msk)) : -1;
}

// delta_1 reduction (R11 core, known-good) with fused scatter prologue:
// this block builds the coboundary rows itself (13k atomicOr to L2),
// accumulates initial lows straight into LDS lowA (atomicMax), and derives
// the clear mask from g_mst/g_eorder -- no k_scat launch, no g_ilow/g_clr
// globals. spiv packs (row<<14)|epoch: one broadcast LDS read per chain step
// yields owner AND claimed-this-pass (mid-write -> requeue next pass).
__global__ void __launch_bounds__(1024) k_reduce(const int* __restrict__ bf,
                                                 const int* __restrict__ sd,
                                                 int nV, int nS,
                                                 float* __restrict__ out) {
  __shared__ int spiv[MAX_T];       // tri position -> (owner row << 14) | epoch
  __shared__ int lowA[MAX_E];
  __shared__ int lists[2][MAX_E];
  __shared__ int tailq[64];
  __shared__ int cnts[2];
  __shared__ int workIdx;
  __shared__ float ssum[16], smax[16];

  int tid = threadIdx.x;
  int lane = tid & 63;
  int wave = tid >> 6;
  int nE = ub_dim(sd, nS, 1) - nV;
  int nT = ub_dim(sd, nS, 2) - nV - nE;

  for (int i = tid; i < nT; i += 1024) spiv[i] = INF_I;
  for (int r = tid; r < nE; r += 1024) lowA[r] = -1;
  if (tid == 0) { cnts[0] = 0; cnts[1] = 0; }
  __syncthreads();

  // ---- scatter prologue: build rows + initial lows (LDS atomicMax) ----
  for (int t = tid; t < nT; t += 1024) {
    int lpos = nT - 1 - g_trank[t];
    size_t base = (size_t)2 * nE + (size_t)3 * t;
    ull bit = 1ull << (lpos & 63);
    int word = lpos >> 6;
    for (int j = 0; j < 3; ++j) {
      int e = bf[base + j] - nV;
      int rr = nE - 1 - g_erank[e];
      atomicOr(&g_rows[(size_t)rr * TW + word], bit);
      atomicMax(&lowA[rr], lpos);
    }
  }
  __syncthreads();
  // clear mask (MST edges) + claims (settled: rows untouched)
  for (int r = tid; r < nE; r += 1024) {
    int e = g_eorder[nE - 1 - r];
    int l = g_mst[e] ? -1 : lowA[r];
    lowA[r] = l;
    if (l >= 0) atomicMin(&spiv[l], (r << EP_BITS) | EP_DONE);
  }
  __syncthreads();
  for (int r = tid; r < nE; r += 1024) {
    int l = lowA[r];
    if (l >= 0 && (spiv[l] >> EP_BITS) != r) { int q = atomicAdd(&cnts[0], 1); lists[0][q] = r; }
  }
  __syncthreads();

  int pass = 0;
  int cnt = cnts[0];
  while (cnt > 0 && pass < 16000) {
    int cur = pass & 1, nxt = cur ^ 1;

    if (cnt <= 8) {
      // ---- serial tail: wave 0 resolves all remaining cascades ----
      // single actor => every owner row is fully written; no epoch checks.
      if (wave == 0) {
        for (int i = lane; i < cnt; i += 64) tailq[i] = lists[cur][i];
        int head = 0, tl = cnt;
        while (head < tl) {
          int r = tailq[head & 63]; head++;
          int l = lowA[r];                   // row's current low (== lost pivot)
          ull wx = 0, wy = 0;
          bool loaded = false;
          for (;;) {
            int p = spiv[l] >> EP_BITS;      // settled winner, p < r
            ull px = 0, py = 0;
            if (lane < 36) {
              ulonglong2 v = *(const ulonglong2*)&g_rows[(size_t)p * TW + 2 * lane];
              px = v.x; py = v.y;
            }
            if (!loaded) {
              if (lane < 36) {
                ulonglong2 v = *(const ulonglong2*)&g_rows[(size_t)r * TW + 2 * lane];
                wx = v.x; wy = v.y;
              }
              loaded = true;
            }
            wx ^= px; wy ^= py;
            l = row_low(wx, wy, lane);
            if (l < 0) break;                // unreachable for uncleared rows
            int old = 0;
            if (lane == 0) old = atomicMin(&spiv[l], (r << EP_BITS) | EP_DONE);
            old = __shfl(old, 0);
            if (old > ((r << EP_BITS) | EP_DONE)) {  // claimed: publish, queue evictee
              if (lane < 36) {
                ulonglong2 v; v.x = wx; v.y = wy;
                *(ulonglong2*)&g_rows[(size_t)r * TW + 2 * lane] = v;
              }
              if (lane == 0) lowA[r] = l;
              if (old != INF_I) { if (lane == 0) tailq[tl & 63] = old >> EP_BITS; tl++; }
              break;
            }
            // lost claim; keep chaining through new owner
          }
        }
      }
      __syncthreads();
      break;
    }

    if (tid == 0) { cnts[nxt] = 0; workIdx = 0; }
    __syncthreads();
    for (;;) {
      int idx = 0;
      if (lane == 0) idx = atomicAdd(&workIdx, 1);
      idx = __shfl(idx, 0);
      if (idx >= cnt) break;
      int r = lists[cur][idx];
      int l = lowA[r];                       // >= 0 for every listed row
      ull wx = 0, wy = 0;
      bool loaded = false, modified = false;
      for (;;) {
        int val = spiv[l];                   // broadcast: owner + epoch in one read
        int p = val >> EP_BITS;              // p < r always
        if ((val & EP_MASK) == pass) {       // owner claimed this pass: mid-write
          if (lane == 0) { int q = atomicAdd(&cnts[nxt], 1); lists[nxt][q] = r; }
          break;
        }
        ull px = 0, py = 0;
        if (lane < 36) {
          ulonglong2 v = *(const ulonglong2*)&g_rows[(size_t)p * TW + 2 * lane];
          px = v.x; py = v.y;
        }
        if (!loaded) {
          if (lane < 36) {
            ulonglong2 v = *(const ulonglong2*)&g_rows[(size_t)r * TW + 2 * lane];
            wx = v.x; wy = v.y;
          }
          loaded = true;
        }
        wx ^= px; wy ^= py;
        modified = true;
        l = row_low(wx, wy, lane);
        if (lane == 0) lowA[r] = l;
        if (l < 0) break;                    // unreachable for uncleared rows
        int myval = (r << EP_BITS) | pass;
        int old = 0;
        if (lane == 0) old = atomicMin(&spiv[l], myval);
        old = __shfl(old, 0);
        if (old > myval) {                   // claimed; evictee reacts next pass
          if (old != INF_I && lane == 0) { int q = atomicAdd(&cnts[nxt], 1); lists[nxt][q] = old >> EP_BITS; }
          break;
        }
        // lost claim; loop re-reads spiv[l] (epoch check covers mid-pass owner)
      }
      if (modified && l >= 0 && lane < 36) {
        ulonglong2 v; v.x = wx; v.y = wy;
        *(ulonglong2*)&g_rows[(size_t)r * TW + 2 * lane] = v;
      }
    }
    __syncthreads();
    cnt = cnts[nxt];
    pass++;
  }

  // epilogue: pair (edge rank nE-1-r, tri rank nT-1-l); loss1 = sum - max
  float sum = 0.f, mx = 0.f;
  for (int l = tid; l < nT; l += 1024) {
    int v = spiv[l];
    if (v != INF_I) {
      int r = v >> EP_BITS;
      float len = g_ef[nE - 1 - r] - g_tf[nT - 1 - l];
      sum += len;
      mx = fmaxf(mx, len);
    }
  }
  #pragma unroll
  for (int off = 32; off; off >>= 1) {
    sum += __shfl_xor(sum, off, 64);
    mx = fmaxf(mx, __shfl_xor(mx, off, 64));
  }
  if (lane == 0) { ssum[wave] = sum; smax[wave] = mx; }
  __syncthreads();
  if (tid == 0) {
    float S = 0.f, M = 0.f;
    for (int i = 0; i < 16; ++i) { S += ssum[i]; M = fmaxf(M, smax[i]); }
    out[0] = g_loss0 + S - M;
  }
}

extern "C" void kernel_launch(void* const* d_in, const int* in_sizes, int n_in,
                              void* d_out, int out_size, void* d_ws, size_t ws_size,
                              hipStream_t stream) {
  const float* beta = (const float*)d_in[0];
  const int*   sv   = (const int*)d_in[1];
  const int*   sd   = (const int*)d_in[2];
  const int*   bf   = (const int*)d_in[4];
  float* out = (float*)d_out;

  int nV = in_sizes[0];
  int nS = in_sizes[2];

  k_main1<<<RB_E + RB_T + 1 + RB_C, 256, 0, stream>>>(beta, sv, sd, nV, nS);
  k_reduce<<<1, 1024, 0, stream>>>(bf, sd, nV, nS, out);
}

// Round 14
// 182.878 us; speedup vs baseline: 1.0531x; 1.0531x over previous
//
#include <hip/hip_runtime.h>
#include <stdint.h>

// Fixed 8x8x8 grid complex: nV=512, nE=2863, nT=4410, nTet=2058, nS=9843.
// Dim-1 pairs via COHOMOLOGY (coboundary delta_1) + clearing of MST edges:
// rows = edges (reverse filtration order), bits = triangles (reverse order).
// Negative (MST) edges' rows would reduce to zero -> cleared upfront.
#define MAX_E 3072
#define MAX_T 4608
#define MAX_V 1024
#define TW    72     // u64 words per row >= ceil(nT/64); 2 words/lane, lanes 0..35
#define INF_I 0x7fffffff
#define RB_E  12     // edge-rank blocks
#define RB_T  18     // tri-rank blocks
#define RB_C  24     // clear blocks
#define SCAT_B 5     // scatter blocks in fused kernel (1024 thr each)
// spiv packing: value = (row << 14) | epoch. atomicMin orders by row (high
// bits); epoch==current pass marks "claimed this pass, row may be mid-write".
#define EP_BITS  14
#define EP_MASK  0x3FFF
#define EP_DONE  0x3FFF   // settled marker (pass counter capped below it)

typedef unsigned long long ull;

__device__ int   g_erank[MAX_E];             // edge local idx -> rank (f desc, idx asc)
__device__ int   g_eorder[MAX_E];            // rank -> edge local idx
__device__ float g_ef[MAX_E];                // f by edge rank
__device__ int   g_trank[MAX_T];             // tri local idx -> rank
__device__ float g_tf[MAX_T];                // f by tri rank
__device__ __attribute__((aligned(16))) ull g_rows[(size_t)MAX_E * TW];
__device__ int   g_mst[MAX_E];               // edge idx -> 1 if MST (negative) edge
__device__ int   g_clr[MAX_E];               // row rr -> 1 if cleared
__device__ int   g_ilow[MAX_E];              // row rr -> initial low (max bit), -1 if none
__device__ int   g_done;                     // producer-blocks done counter (reset by k_main1)
__device__ float g_loss0;

// sd is sorted (verts, edges, tris, tets): first index with dim > d.
__device__ __forceinline__ int ub_dim(const int* __restrict__ sd, int nS, int d) {
  int lo = 0, hi = nS;
  while (lo < hi) { int mid = (lo + hi) >> 1; if (sd[mid] <= d) lo = mid + 1; else hi = mid; }
  return lo;
}

// Orderable key: key_j > key_i  <=>  (fj > fi) || (fj == fi && j < i).
__device__ __forceinline__ ull rank_key(float f, int j) {
  unsigned bb = __float_as_uint(f);
  unsigned ord = (bb & 0x80000000u) ? ~bb : (bb | 0x80000000u);
  return ((ull)ord << 32) | (ull)(0xffffffffu - (unsigned)j);
}

// Count keys > ki with 4 independent ds_read_b128 in flight per iteration
// (ILP hides LDS latency: rank blocks run few waves/SIMD, limited TLP).
__device__ __forceinline__ int rank_count64(const ull* __restrict__ sk, int n, ull ki) {
  int r = 0, j = 0;
  for (; j + 8 <= n; j += 8) {
    ulonglong2 a = *(const ulonglong2*)(sk + j);
    ulonglong2 b = *(const ulonglong2*)(sk + j + 2);
    ulonglong2 c = *(const ulonglong2*)(sk + j + 4);
    ulonglong2 d = *(const ulonglong2*)(sk + j + 6);
    r += (int)(a.x > ki) + (int)(a.y > ki) + (int)(b.x > ki) + (int)(b.y > ki)
       + (int)(c.x > ki) + (int)(c.y > ki) + (int)(d.x > ki) + (int)(d.y > ki);
  }
  for (; j < n; ++j) r += (int)(sk[j] > ki);
  return r;
}

// Find with path halving. Races with concurrent halving writes are benign
// (every write installs an ancestor; hooks are barrier-separated from finds).
__device__ __forceinline__ int uf_find(int* par, int x) {
  for (;;) {
    int p = par[x];
    if (p == x) return x;
    int gp = par[p];
    if (p != gp) par[x] = gp;
    x = gp;
  }
}

// K1: independent roles — edge ranks | tri ranks | UF (Boruvka) | row clear.
// UF is rank-independent (writes g_mst by edge idx), so all roles overlap.
union SharedK1 {
  struct { alignas(16) ull sk[MAX_T]; } rank;
  struct {
    int par[MAX_V]; ull cand[MAX_V]; int hookTo[MAX_V];
    int eu[MAX_E], ev2[MAX_E];
    float efv[MAX_E];
    unsigned int ekey[MAX_E];
    unsigned short alive[2][MAX_E];
    unsigned char mstf[MAX_E];
  } uf;
};

__global__ void __launch_bounds__(256) k_main1(const float* __restrict__ beta,
                                               const int* __restrict__ sv,
                                               const int* __restrict__ sd,
                                               int nV, int nS) {
  __shared__ SharedK1 sh;
  __shared__ float aS[4], aM[4], aW[4];
  __shared__ int nNext;
  int b = blockIdx.x, tid = threadIdx.x;
  int nE = ub_dim(sd, nS, 1) - nV;

  if (b < RB_E) {
    // ---- edge ranks via u64-key counting ----
    int i = b * 256 + tid;
    float fi = 0.f;
    for (int j = tid; j < nE; j += 256) {     // j==i hit here (j ≡ tid mod 256)
      const int* p = &sv[(size_t)(nV + j) * 4];
      float fj = fminf(beta[p[0]], beta[p[1]]);
      if (j == i) fi = fj;
      sh.rank.sk[j] = rank_key(fj, j);
    }
    __syncthreads();
    if (i >= nE) return;
    int r = rank_count64(sh.rank.sk, nE, sh.rank.sk[i]);
    g_erank[i] = r;
    g_eorder[r] = i;
    g_ef[r] = fi;
    return;
  }
  if (b < RB_E + RB_T) {
    // ---- tri ranks ----
    int nT = ub_dim(sd, nS, 2) - nV - nE;
    int base = nV + nE;
    int i = (b - RB_E) * 256 + tid;
    float fi = 0.f;
    for (int j = tid; j < nT; j += 256) {
      const int* p = &sv[(size_t)(base + j) * 4];
      float fj = fminf(fminf(beta[p[0]], beta[p[1]]), beta[p[2]]);
      if (j == i) fi = fj;
      sh.rank.sk[j] = rank_key(fj, j);
    }
    __syncthreads();
    if (i >= nT) return;
    int r = rank_count64(sh.rank.sk, nT, sh.rank.sk[i]);
    g_trank[i] = r;
    g_tf[r] = fi;
    return;
  }
  if (b > RB_E + RB_T) {
    // ---- clear g_rows + init g_ilow ----
    size_t i = (size_t)(b - RB_E - RB_T - 1) * 256 + tid;
    size_t stride = (size_t)RB_C * 256;
    for (size_t k = i; k < (size_t)MAX_E * TW; k += stride) g_rows[k] = 0ull;
    for (size_t k = i; k < MAX_E; k += stride) g_ilow[k] = -1;
    return;
  }

  // ---- UF role: loss0 = sum_v f(v) - max_v f(v) - W(canonical max ST).
  // Boruvka with STRICT keys (f desc, idx asc) == Kruskal's negative edge set.
  // Path-halving finds, 2 compress sweeps, terminate on empty alive list.
  int lane = tid & 63, wave = tid >> 6;
  if (tid == 0) g_done = 0;                   // reset fused-kernel handshake
  int* par = sh.uf.par;
  for (int v = tid; v < nV; v += 256) par[v] = v;
  for (int e = tid; e < nE; e += 256) {
    int u = sv[(size_t)(nV + e) * 4];
    int v = sv[(size_t)(nV + e) * 4 + 1];
    sh.uf.eu[e] = u; sh.uf.ev2[e] = v;
    float fe = fminf(beta[u], beta[v]);
    sh.uf.efv[e] = fe;
    unsigned int bb = __float_as_uint(fe);
    sh.uf.ekey[e] = (bb & 0x80000000u) ? ~bb : (bb | 0x80000000u);  // orderable
    sh.uf.alive[0][e] = (unsigned short)e;
    sh.uf.mstf[e] = 0;
  }
  float s = 0.f, m = -3.0e38f;
  for (int v = tid; v < nV; v += 256) { float fv = beta[v]; s += fv; m = fmaxf(m, fv); }
  float W = 0.f;
  int nAlive = nE, cur = 0;
  __syncthreads();
  for (int phase = 0; phase < 20 && nAlive > 0; ++phase) {
    for (int v = tid; v < nV; v += 256) sh.uf.cand[v] = 0ull;
    if (tid == 0) nNext = 0;
    __syncthreads();
    for (int i0 = 0; i0 < nAlive; i0 += 256) {
      int i = i0 + tid;
      int e = -1;
      bool cross = false;
      int ra = 0, rb = 0;
      if (i < nAlive) {
        e = sh.uf.alive[cur][i];
        ra = uf_find(par, sh.uf.eu[e]);
        rb = uf_find(par, sh.uf.ev2[e]);
        cross = (ra != rb);
      }
      ull mb = __ballot(cross);
      int base = 0;
      if (lane == 0 && mb) base = atomicAdd(&nNext, __popcll(mb));
      base = __shfl(base, 0);
      if (cross) {
        int off = __popcll(mb & ((1ull << lane) - 1ull));
        sh.uf.alive[cur ^ 1][base + off] = (unsigned short)e;
        // key: larger f wins; tie -> SMALLER edge idx wins (canonical order)
        ull key = ((ull)sh.uf.ekey[e] << 32) | (ull)(0xffffffffu - (unsigned)e);
        atomicMax(&sh.uf.cand[ra], key);
        atomicMax(&sh.uf.cand[rb], key);
      }
    }
    __syncthreads();
    for (int v = tid; v < nV; v += 256) {
      int t = -1;
      ull cv = sh.uf.cand[v];
      if (par[v] == v && cv) {
        int e = (int)(0xffffffffu - (unsigned)(cv & 0xffffffffu));
        int ra = uf_find(par, sh.uf.eu[e]);
        int rb = uf_find(par, sh.uf.ev2[e]);
        int other = (ra == v) ? rb : ra;
        if (sh.uf.cand[other] != cv || v < other) t = other;  // break 2-cycles
      }
      sh.uf.hookTo[v] = t;
    }
    __syncthreads();
    for (int v = tid; v < nV; v += 256) {
      int t = sh.uf.hookTo[v];
      if (t >= 0) {
        par[v] = t;
        int e = (int)(0xffffffffu - (unsigned)(sh.uf.cand[v] & 0xffffffffu));
        W += sh.uf.efv[e];
        sh.uf.mstf[e] = 1;                   // negative edge
      }
    }
    __syncthreads();
    for (int it = 0; it < 2; ++it) {
      for (int v = tid; v < nV; v += 256) {
        int p = par[v]; int gp = par[p];
        if (p != gp) par[v] = gp;
      }
      __syncthreads();
    }
    nAlive = nNext;
    cur ^= 1;
    __syncthreads();                          // nNext read-before-reset fence
  }
  __syncthreads();
  // write MST flags once
  for (int e = tid; e < nE; e += 256) g_mst[e] = sh.uf.mstf[e];
  #pragma unroll
  for (int off = 32; off; off >>= 1) {
    s += __shfl_xor(s, off, 64);
    m = fmaxf(m, __shfl_xor(m, off, 64));
    W += __shfl_xor(W, off, 64);
  }
  if (lane == 0) { aS[wave] = s; aM[wave] = m; aW[wave] = W; }
  __syncthreads();
  if (tid == 0) {
    float S = 0.f, M = -3.0e38f, WW = 0.f;
    for (int i = 0; i < 4; ++i) { S += aS[i]; M = fmaxf(M, aM[i]); WW += aW[i]; }
    g_loss0 = S - M - WW;
  }
}

__device__ __forceinline__ int row_low(ull x, ull y, int lane) {
  ull msk = __ballot((x | y) != 0ull);
  int hb = y ? (lane * 128 + 127 - __clzll(y)) : (lane * 128 + 63 - __clzll(x | 1ull));
  return msk ? __shfl(hb, 63 - __clzll(msk)) : -1;
}

// Fused scatter+reduce: blocks 1..SCAT_B scatter coboundary rows (multi-block
// -> atomics spread over CUs/XCDs, the R13 single-block mistake avoided);
// block SCAT_B+1 translates MST flags to cleared rows. Each producer block
// does __threadfence() + atomicAdd(g_done). Block 0 inits its LDS, polls
// g_done (7 blocks << 256 CUs -> co-resident; device-scope atomics + fences
// per G12/G16), then runs the R11 reduce core verbatim.
__global__ void __launch_bounds__(1024) k_scatred(const int* __restrict__ bf,
                                                  const int* __restrict__ sd,
                                                  int nV, int nS,
                                                  float* __restrict__ out) {
  int tid = threadIdx.x;
  int nE = ub_dim(sd, nS, 1) - nV;
  int nT = ub_dim(sd, nS, 2) - nV - nE;

  if (blockIdx.x >= 1 && blockIdx.x <= SCAT_B) {
    // ---- scatter role ----
    int t = (blockIdx.x - 1) * 1024 + tid;
    if (t < nT) {
      int lpos = nT - 1 - g_trank[t];
      size_t base = (size_t)2 * nE + (size_t)3 * t;
      ull bit = 1ull << (lpos & 63);
      int word = lpos >> 6;
      for (int j = 0; j < 3; ++j) {
        int e = bf[base + j] - nV;
        int rr = nE - 1 - g_erank[e];
        atomicOr(&g_rows[(size_t)rr * TW + word], bit);
        atomicMax(&g_ilow[rr], lpos);
      }
    }
    __syncthreads();
    __threadfence();                          // release: all atomics visible
    if (tid == 0) atomicAdd(&g_done, 1);
    return;
  }
  if (blockIdx.x == SCAT_B + 1) {
    // ---- translate role: MST flags -> cleared rows (rank space) ----
    for (int r = tid; r < nE; r += 1024)
      g_clr[nE - 1 - r] = g_mst[g_eorder[r]];
    __syncthreads();
    __threadfence();
    if (tid == 0) atomicAdd(&g_done, 1);
    return;
  }

  // ---- block 0: reduce (R11 core) ----
  __shared__ int spiv[MAX_T];       // tri position -> (owner row << 14) | epoch
  __shared__ int lowA[MAX_E];
  __shared__ int lists[2][MAX_E];
  __shared__ int tailq[64];
  __shared__ int cnts[2];
  __shared__ int workIdx;
  __shared__ float ssum[16], smax[16];

  int lane = tid & 63;
  int wave = tid >> 6;

  for (int i = tid; i < nT; i += 1024) spiv[i] = INF_I;
  if (tid == 0) { cnts[0] = 0; cnts[1] = 0; }
  __syncthreads();
  // wait for producers (co-resident; device-scope counter)
  if (tid == 0) { while (atomicAdd(&g_done, 0) < SCAT_B + 1) { } }
  __syncthreads();
  __threadfence();                            // acquire: see producer writes

  // initial lows from g_ilow (no row reads) + claims (settled: rows untouched)
  for (int r = tid; r < nE; r += 1024) {
    int l = g_clr[r] ? -1 : g_ilow[r];
    lowA[r] = l;
    if (l >= 0) atomicMin(&spiv[l], (r << EP_BITS) | EP_DONE);
  }
  __syncthreads();
  for (int r = tid; r < nE; r += 1024) {
    int l = lowA[r];
    if (l >= 0 && (spiv[l] >> EP_BITS) != r) { int q = atomicAdd(&cnts[0], 1); lists[0][q] = r; }
  }
  __syncthreads();

  int pass = 0;
  int cnt = cnts[0];
  while (cnt > 0 && pass < 16000) {
    int cur = pass & 1, nxt = cur ^ 1;

    if (cnt <= 8) {
      // ---- serial tail: wave 0 resolves all remaining cascades ----
      // single actor => every owner row is fully written; no epoch checks.
      if (wave == 0) {
        for (int i = lane; i < cnt; i += 64) tailq[i] = lists[cur][i];
        int head = 0, tl = cnt;
        while (head < tl) {
          int r = tailq[head & 63]; head++;
          int l = lowA[r];                   // row's current low (== lost pivot)
          ull wx = 0, wy = 0;
          bool loaded = false;
          for (;;) {
            int p = spiv[l] >> EP_BITS;      // settled winner, p < r
            ull px = 0, py = 0;
            if (lane < 36) {
              ulonglong2 v = *(const ulonglong2*)&g_rows[(size_t)p * TW + 2 * lane];
              px = v.x; py = v.y;
            }
            if (!loaded) {
              if (lane < 36) {
                ulonglong2 v = *(const ulonglong2*)&g_rows[(size_t)r * TW + 2 * lane];
                wx = v.x; wy = v.y;
              }
              loaded = true;
            }
            wx ^= px; wy ^= py;
            l = row_low(wx, wy, lane);
            if (l < 0) break;                // unreachable for uncleared rows
            int old = 0;
            if (lane == 0) old = atomicMin(&spiv[l], (r << EP_BITS) | EP_DONE);
            old = __shfl(old, 0);
            if (old > ((r << EP_BITS) | EP_DONE)) {  // claimed: publish, queue evictee
              if (lane < 36) {
                ulonglong2 v; v.x = wx; v.y = wy;
                *(ulonglong2*)&g_rows[(size_t)r * TW + 2 * lane] = v;
              }
              if (lane == 0) lowA[r] = l;
              if (old != INF_I) { if (lane == 0) tailq[tl & 63] = old >> EP_BITS; tl++; }
              break;
            }
            // lost claim; keep chaining through new owner
          }
        }
      }
      __syncthreads();
      break;
    }

    if (tid == 0) { cnts[nxt] = 0; workIdx = 0; }
    __syncthreads();
    for (;;) {
      int idx = 0;
      if (lane == 0) idx = atomicAdd(&workIdx, 1);
      idx = __shfl(idx, 0);
      if (idx >= cnt) break;
      int r = lists[cur][idx];
      int l = lowA[r];                       // >= 0 for every listed row
      ull wx = 0, wy = 0;
      bool loaded = false, modified = false;
      for (;;) {
        int val = spiv[l];                   // broadcast: owner + epoch in one read
        int p = val >> EP_BITS;              // p < r always
        if ((val & EP_MASK) == pass) {       // owner claimed this pass: mid-write
          if (lane == 0) { int q = atomicAdd(&cnts[nxt], 1); lists[nxt][q] = r; }
          break;
        }
        ull px = 0, py = 0;
        if (lane < 36) {
          ulonglong2 v = *(const ulonglong2*)&g_rows[(size_t)p * TW + 2 * lane];
          px = v.x; py = v.y;
        }
        if (!loaded) {
          if (lane < 36) {
            ulonglong2 v = *(const ulonglong2*)&g_rows[(size_t)r * TW + 2 * lane];
            wx = v.x; wy = v.y;
          }
          loaded = true;
        }
        wx ^= px; wy ^= py;
        modified = true;
        l = row_low(wx, wy, lane);
        if (lane == 0) lowA[r] = l;
        if (l < 0) break;                    // unreachable for uncleared rows
        int myval = (r << EP_BITS) | pass;
        int old = 0;
        if (lane == 0) old = atomicMin(&spiv[l], myval);
        old = __shfl(old, 0);
        if (old > myval) {                   // claimed; evictee reacts next pass
          if (old != INF_I && lane == 0) { int q = atomicAdd(&cnts[nxt], 1); lists[nxt][q] = old >> EP_BITS; }
          break;
        }
        // lost claim; loop re-reads spiv[l] (epoch check covers mid-pass owner)
      }
      if (modified && l >= 0 && lane < 36) {
        ulonglong2 v; v.x = wx; v.y = wy;
        *(ulonglong2*)&g_rows[(size_t)r * TW + 2 * lane] = v;
      }
    }
    __syncthreads();
    cnt = cnts[nxt];
    pass++;
  }

  // epilogue: pair (edge rank nE-1-r, tri rank nT-1-l); loss1 = sum - max
  float sum = 0.f, mx = 0.f;
  for (int l = tid; l < nT; l += 1024) {
    int v = spiv[l];
    if (v != INF_I) {
      int r = v >> EP_BITS;
      float len = g_ef[nE - 1 - r] - g_tf[nT - 1 - l];
      sum += len;
      mx = fmaxf(mx, len);
    }
  }
  #pragma unroll
  for (int off = 32; off; off >>= 1) {
    sum += __shfl_xor(sum, off, 64);
    mx = fmaxf(mx, __shfl_xor(mx, off, 64));
  }
  if (lane == 0) { ssum[wave] = sum; smax[wave] = mx; }
  __syncthreads();
  if (tid == 0) {
    float S = 0.f, M = 0.f;
    for (int i = 0; i < 16; ++i) { S += ssum[i]; M = fmaxf(M, smax[i]); }
    out[0] = g_loss0 + S - M;
  }
}

extern "C" void kernel_launch(void* const* d_in, const int* in_sizes, int n_in,
                              void* d_out, int out_size, void* d_ws, size_t ws_size,
                              hipStream_t stream) {
  const float* beta = (const float*)d_in[0];
  const int*   sv   = (const int*)d_in[1];
  const int*   sd   = (const int*)d_in[2];
  const int*   bf   = (const int*)d_in[4];
  float* out = (float*)d_out;

  int nV = in_sizes[0];
  int nS = in_sizes[2];

  k_main1<<<RB_E + RB_T + 1 + RB_C, 256, 0, stream>>>(beta, sv, sd, nV, nS);
  k_scatred<<<SCAT_B + 2, 1024, 0, stream>>>(bf, sd, nV, nS, out);
}

// Round 15
// 170.940 us; speedup vs baseline: 1.1266x; 1.0698x over previous
//
#include <hip/hip_runtime.h>
#include <stdint.h>

// Fixed 8x8x8 grid complex: nV=512, nE=2863, nT=4410, nTet=2058, nS=9843.
// Dim-1 pairs via COHOMOLOGY (coboundary delta_1) + clearing of MST edges:
// rows = edges (reverse filtration order), bits = triangles (reverse order).
// Negative (MST) edges' rows would reduce to zero -> cleared upfront.
#define MAX_E 3072
#define MAX_T 4608
#define MAX_V 1024
#define TW    72     // u64 words per row >= ceil(nT/64); 2 words/lane, lanes 0..35
#define INF_I 0x7fffffff
#define RB_E  12     // edge-rank blocks
#define RB_T  18     // tri-rank blocks
#define RB_C  24     // clear blocks
#define TBLK  18     // scatter blocks = ceil(MAX_T/256)
// spiv packing: value = (row << 14) | epoch. atomicMin orders by row (high
// bits); epoch==current pass marks "claimed this pass, row may be mid-write".
#define EP_BITS  14
#define EP_MASK  0x3FFF
#define EP_DONE  0x3FFF   // settled marker (pass counter capped below it)

typedef unsigned long long ull;

__device__ int   g_erank[MAX_E];             // edge local idx -> rank (f desc, idx asc)
__device__ int   g_eorder[MAX_E];            // rank -> edge local idx
__device__ float g_ef[MAX_E];                // f by edge rank
__device__ int   g_trank[MAX_T];             // tri local idx -> rank
__device__ float g_tf[MAX_T];                // f by tri rank
__device__ __attribute__((aligned(16))) ull g_rows[(size_t)MAX_E * TW];
__device__ int   g_mst[MAX_E];               // edge idx -> 1 if MST (negative) edge
__device__ int   g_clr[MAX_E];               // row rr -> 1 if cleared
__device__ int   g_ilow[MAX_E];              // row rr -> initial low (max bit), -1 if none
__device__ float g_loss0;

// sd is sorted (verts, edges, tris, tets): first index with dim > d.
__device__ __forceinline__ int ub_dim(const int* __restrict__ sd, int nS, int d) {
  int lo = 0, hi = nS;
  while (lo < hi) { int mid = (lo + hi) >> 1; if (sd[mid] <= d) lo = mid + 1; else hi = mid; }
  return lo;
}

// Orderable key: key_j > key_i  <=>  (fj > fi) || (fj == fi && j < i).
__device__ __forceinline__ ull rank_key(float f, int j) {
  unsigned bb = __float_as_uint(f);
  unsigned ord = (bb & 0x80000000u) ? ~bb : (bb | 0x80000000u);
  return ((ull)ord << 32) | (ull)(0xffffffffu - (unsigned)j);
}

// Count keys > ki with 4 independent ds_read_b128 in flight per iteration
// (ILP hides LDS latency: rank blocks run 1 wave/SIMD, no TLP available).
__device__ __forceinline__ int rank_count64(const ull* __restrict__ sk, int n, ull ki) {
  int r = 0, j = 0;
  for (; j + 8 <= n; j += 8) {
    ulonglong2 a = *(const ulonglong2*)(sk + j);
    ulonglong2 b = *(const ulonglong2*)(sk + j + 2);
    ulonglong2 c = *(const ulonglong2*)(sk + j + 4);
    ulonglong2 d = *(const ulonglong2*)(sk + j + 6);
    r += (int)(a.x > ki) + (int)(a.y > ki) + (int)(b.x > ki) + (int)(b.y > ki)
       + (int)(c.x > ki) + (int)(c.y > ki) + (int)(d.x > ki) + (int)(d.y > ki);
  }
  for (; j < n; ++j) r += (int)(sk[j] > ki);
  return r;
}

// Find with path halving. Races with concurrent halving writes are benign
// (every write installs an ancestor; hooks are barrier-separated from finds).
__device__ __forceinline__ int uf_find(int* par, int x) {
  for (;;) {
    int p = par[x];
    if (p == x) return x;
    int gp = par[p];
    if (p != gp) par[x] = gp;
    x = gp;
  }
}

// K1: independent roles — edge ranks | tri ranks | UF (Boruvka) | row clear.
// UF is rank-independent (writes g_mst by edge idx), so all roles overlap.
union SharedK1 {
  struct { alignas(16) ull sk[MAX_T]; } rank;
  struct {
    int par[MAX_V]; ull cand[MAX_V]; int hookTo[MAX_V];
    int eu[MAX_E], ev2[MAX_E];
    float efv[MAX_E];
    unsigned int ekey[MAX_E];
    unsigned short alive[2][MAX_E];
    unsigned char mstf[MAX_E];
  } uf;
};

__global__ void __launch_bounds__(256) k_main1(const float* __restrict__ beta,
                                               const int* __restrict__ sv,
                                               const int* __restrict__ sd,
                                               int nV, int nS) {
  __shared__ SharedK1 sh;
  __shared__ float aS[4], aM[4], aW[4];
  __shared__ int nNext;
  int b = blockIdx.x, tid = threadIdx.x;
  int nE = ub_dim(sd, nS, 1) - nV;

  if (b < RB_E) {
    // ---- edge ranks via u64-key counting ----
    int i = b * 256 + tid;
    float fi = 0.f;
    for (int j = tid; j < nE; j += 256) {     // j==i hit here (j ≡ tid mod 256)
      const int* p = &sv[(size_t)(nV + j) * 4];
      float fj = fminf(beta[p[0]], beta[p[1]]);
      if (j == i) fi = fj;
      sh.rank.sk[j] = rank_key(fj, j);
    }
    __syncthreads();
    if (i >= nE) return;
    int r = rank_count64(sh.rank.sk, nE, sh.rank.sk[i]);
    g_erank[i] = r;
    g_eorder[r] = i;
    g_ef[r] = fi;
    return;
  }
  if (b < RB_E + RB_T) {
    // ---- tri ranks ----
    int nT = ub_dim(sd, nS, 2) - nV - nE;
    int base = nV + nE;
    int i = (b - RB_E) * 256 + tid;
    float fi = 0.f;
    for (int j = tid; j < nT; j += 256) {
      const int* p = &sv[(size_t)(base + j) * 4];
      float fj = fminf(fminf(beta[p[0]], beta[p[1]]), beta[p[2]]);
      if (j == i) fi = fj;
      sh.rank.sk[j] = rank_key(fj, j);
    }
    __syncthreads();
    if (i >= nT) return;
    int r = rank_count64(sh.rank.sk, nT, sh.rank.sk[i]);
    g_trank[i] = r;
    g_tf[r] = fi;
    return;
  }
  if (b > RB_E + RB_T) {
    // ---- clear g_rows + init g_ilow ----
    size_t i = (size_t)(b - RB_E - RB_T - 1) * 256 + tid;
    size_t stride = (size_t)RB_C * 256;
    for (size_t k = i; k < (size_t)MAX_E * TW; k += stride) g_rows[k] = 0ull;
    for (size_t k = i; k < MAX_E; k += stride) g_ilow[k] = -1;
    return;
  }

  // ---- UF role: loss0 = sum_v f(v) - max_v f(v) - W(canonical max ST).
  // Boruvka with STRICT keys (f desc, idx asc) == Kruskal's negative edge set.
  // Path-halving finds, 2 compress sweeps, terminate on empty alive list.
  int lane = tid & 63, wave = tid >> 6;
  int* par = sh.uf.par;
  for (int v = tid; v < nV; v += 256) par[v] = v;
  for (int e = tid; e < nE; e += 256) {
    int u = sv[(size_t)(nV + e) * 4];
    int v = sv[(size_t)(nV + e) * 4 + 1];
    sh.uf.eu[e] = u; sh.uf.ev2[e] = v;
    float fe = fminf(beta[u], beta[v]);
    sh.uf.efv[e] = fe;
    unsigned int bb = __float_as_uint(fe);
    sh.uf.ekey[e] = (bb & 0x80000000u) ? ~bb : (bb | 0x80000000u);  // orderable
    sh.uf.alive[0][e] = (unsigned short)e;
    sh.uf.mstf[e] = 0;
  }
  float s = 0.f, m = -3.0e38f;
  for (int v = tid; v < nV; v += 256) { float fv = beta[v]; s += fv; m = fmaxf(m, fv); }
  float W = 0.f;
  int nAlive = nE, cur = 0;
  __syncthreads();
  for (int phase = 0; phase < 20 && nAlive > 0; ++phase) {
    for (int v = tid; v < nV; v += 256) sh.uf.cand[v] = 0ull;
    if (tid == 0) nNext = 0;
    __syncthreads();
    for (int i0 = 0; i0 < nAlive; i0 += 256) {
      int i = i0 + tid;
      int e = -1;
      bool cross = false;
      int ra = 0, rb = 0;
      if (i < nAlive) {
        e = sh.uf.alive[cur][i];
        ra = uf_find(par, sh.uf.eu[e]);
        rb = uf_find(par, sh.uf.ev2[e]);
        cross = (ra != rb);
      }
      ull mb = __ballot(cross);
      int base = 0;
      if (lane == 0 && mb) base = atomicAdd(&nNext, __popcll(mb));
      base = __shfl(base, 0);
      if (cross) {
        int off = __popcll(mb & ((1ull << lane) - 1ull));
        sh.uf.alive[cur ^ 1][base + off] = (unsigned short)e;
        // key: larger f wins; tie -> SMALLER edge idx wins (canonical order)
        ull key = ((ull)sh.uf.ekey[e] << 32) | (ull)(0xffffffffu - (unsigned)e);
        atomicMax(&sh.uf.cand[ra], key);
        atomicMax(&sh.uf.cand[rb], key);
      }
    }
    __syncthreads();
    for (int v = tid; v < nV; v += 256) {
      int t = -1;
      ull cv = sh.uf.cand[v];
      if (par[v] == v && cv) {
        int e = (int)(0xffffffffu - (unsigned)(cv & 0xffffffffu));
        int ra = uf_find(par, sh.uf.eu[e]);
        int rb = uf_find(par, sh.uf.ev2[e]);
        int other = (ra == v) ? rb : ra;
        if (sh.uf.cand[other] != cv || v < other) t = other;  // break 2-cycles
      }
      sh.uf.hookTo[v] = t;
    }
    __syncthreads();
    for (int v = tid; v < nV; v += 256) {
      int t = sh.uf.hookTo[v];
      if (t >= 0) {
        par[v] = t;
        int e = (int)(0xffffffffu - (unsigned)(sh.uf.cand[v] & 0xffffffffu));
        W += sh.uf.efv[e];
        sh.uf.mstf[e] = 1;                   // negative edge
      }
    }
    __syncthreads();
    for (int it = 0; it < 2; ++it) {
      for (int v = tid; v < nV; v += 256) {
        int p = par[v]; int gp = par[p];
        if (p != gp) par[v] = gp;
      }
      __syncthreads();
    }
    nAlive = nNext;
    cur ^= 1;
    __syncthreads();                          // nNext read-before-reset fence
  }
  __syncthreads();
  // write MST flags once
  for (int e = tid; e < nE; e += 256) g_mst[e] = sh.uf.mstf[e];
  #pragma unroll
  for (int off = 32; off; off >>= 1) {
    s += __shfl_xor(s, off, 64);
    m = fmaxf(m, __shfl_xor(m, off, 64));
    W += __shfl_xor(W, off, 64);
  }
  if (lane == 0) { aS[wave] = s; aM[wave] = m; aW[wave] = W; }
  __syncthreads();
  if (tid == 0) {
    float S = 0.f, M = -3.0e38f, WW = 0.f;
    for (int i = 0; i < 4; ++i) { S += aS[i]; M = fmaxf(M, aM[i]); WW += aW[i]; }
    g_loss0 = S - M - WW;
  }
}

// K2: blocks [0,TBLK) scatter coboundary rows + accumulate each row's initial
// low via atomicMax; block TBLK translates MST flags into cleared-row flags.
__global__ void __launch_bounds__(256) k_scat(const int* __restrict__ bf,
                                              const int* __restrict__ sd,
                                              int nV, int nS) {
  int nE = ub_dim(sd, nS, 1) - nV;
  int tid = threadIdx.x;
  if (blockIdx.x == TBLK) {
    for (int r = tid; r < nE; r += 256)
      g_clr[nE - 1 - r] = g_mst[g_eorder[r]];
    return;
  }
  int nT = ub_dim(sd, nS, 2) - nV - nE;
  int t = blockIdx.x * 256 + tid;
  if (t >= nT) return;
  int lpos = nT - 1 - g_trank[t];
  size_t base = (size_t)2 * nE + (size_t)3 * t;
  ull bit = 1ull << (lpos & 63);
  int word = lpos >> 6;
  for (int j = 0; j < 3; ++j) {
    int e = bf[base + j] - nV;
    int rr = nE - 1 - g_erank[e];
    atomicOr(&g_rows[(size_t)rr * TW + word], bit);
    atomicMax(&g_ilow[rr], lpos);
  }
}

__device__ __forceinline__ int row_low(ull x, ull y, int lane) {
  ull msk = __ballot((x | y) != 0ull);
  int hb = y ? (lane * 128 + 127 - __clzll(y)) : (lane * 128 + 63 - __clzll(x | 1ull));
  return msk ? __shfl(hb, 63 - __clzll(msk)) : -1;
}

// delta_1 reduction with CASCADE COLLAPSE: when a claim evicts a SETTLED
// owner (epoch != current pass => its row is stored & barrier-visible), the
// winning wave adopts the evictee in-place: state = g_rows[op] ^ w (w still
// in registers), then CLAIMS the new low (adopted rows claim-first — their
// fresh low is unclaimed by them). Eviction cascades thus run to completion
// within one pass at L2-read speed instead of one pass per step. Same-pass
// evictees (store possibly in flight) defer to the next pass — the R11
// progress/termination argument carries (low strictly decreases per XOR;
// spiv monotone under atomicMin).
__global__ void __launch_bounds__(1024) k_reduce(const int* __restrict__ sd,
                                                 int nV, int nS,
                                                 float* __restrict__ out) {
  __shared__ int spiv[MAX_T];       // tri position -> (owner row << 14) | epoch
  __shared__ int lowA[MAX_E];
  __shared__ int lists[2][MAX_E];
  __shared__ int tailq[64];
  __shared__ int cnts[2];
  __shared__ int workIdx;
  __shared__ float ssum[16], smax[16];

  int tid = threadIdx.x;
  int lane = tid & 63;
  int wave = tid >> 6;
  int nE = ub_dim(sd, nS, 1) - nV;
  int nT = ub_dim(sd, nS, 2) - nV - nE;

  for (int i = tid; i < nT; i += 1024) spiv[i] = INF_I;
  if (tid == 0) { cnts[0] = 0; cnts[1] = 0; }
  __syncthreads();

  // initial lows from g_ilow (no row reads) + claims (settled: rows untouched)
  for (int r = tid; r < nE; r += 1024) {
    int l = g_clr[r] ? -1 : g_ilow[r];
    lowA[r] = l;
    if (l >= 0) atomicMin(&spiv[l], (r << EP_BITS) | EP_DONE);
  }
  __syncthreads();
  for (int r = tid; r < nE; r += 1024) {
    int l = lowA[r];
    if (l >= 0 && (spiv[l] >> EP_BITS) != r) { int q = atomicAdd(&cnts[0], 1); lists[0][q] = r; }
  }
  __syncthreads();

  int pass = 0;
  int cnt = cnts[0];
  while (cnt > 0 && pass < 16000) {
    int cur = pass & 1, nxt = cur ^ 1;

    if (cnt <= 8) {
      // ---- serial tail: wave 0 resolves all remaining cascades ----
      // single actor => every owner row is fully written; no epoch checks.
      if (wave == 0) {
        for (int i = lane; i < cnt; i += 64) tailq[i] = lists[cur][i];
        int head = 0, tl = cnt;
        while (head < tl) {
          int r = tailq[head & 63]; head++;
          int l = lowA[r];                   // row's current low (== lost pivot)
          ull wx = 0, wy = 0;
          bool loaded = false;
          for (;;) {
            int p = spiv[l] >> EP_BITS;      // settled winner, p < r
            ull px = 0, py = 0;
            if (lane < 36) {
              ulonglong2 v = *(const ulonglong2*)&g_rows[(size_t)p * TW + 2 * lane];
              px = v.x; py = v.y;
            }
            if (!loaded) {
              if (lane < 36) {
                ulonglong2 v = *(const ulonglong2*)&g_rows[(size_t)r * TW + 2 * lane];
                wx = v.x; wy = v.y;
              }
              loaded = true;
            }
            wx ^= px; wy ^= py;
            l = row_low(wx, wy, lane);
            if (l < 0) break;                // unreachable for uncleared rows
            int old = 0;
            if (lane == 0) old = atomicMin(&spiv[l], (r << EP_BITS) | EP_DONE);
            old = __shfl(old, 0);
            if (old > ((r << EP_BITS) | EP_DONE)) {  // claimed: publish, queue evictee
              if (lane < 36) {
                ulonglong2 v; v.x = wx; v.y = wy;
                *(ulonglong2*)&g_rows[(size_t)r * TW + 2 * lane] = v;
              }
              if (lane == 0) lowA[r] = l;
              if (old != INF_I) { if (lane == 0) tailq[tl & 63] = old >> EP_BITS; tl++; }
              break;
            }
            // lost claim; keep chaining through new owner
          }
        }
      }
      __syncthreads();
      break;
    }

    if (tid == 0) { cnts[nxt] = 0; workIdx = 0; }
    __syncthreads();
    for (;;) {
      int idx = 0;
      if (lane == 0) idx = atomicAdd(&workIdx, 1);
      idx = __shfl(idx, 0);
      if (idx >= cnt) break;
      int r = lists[cur][idx];
      int l = lowA[r];                       // >= 0 for every listed row
      ull wx = 0, wy = 0;
      bool loaded = false, modified = false;
      bool do_claim = true;                  // listed rows' first claim provably
      int val = 0;                           // loses and fetches the owner word
      for (;;) {
        if (do_claim) {
          int myval = (r << EP_BITS) | pass;
          int old = 0;
          if (lane == 0) old = atomicMin(&spiv[l], myval);
          old = __shfl(old, 0);
          if (old > myval) {
            // ---- claimed: publish row now (readers defer on epoch==pass) ----
            if (!loaded) {                   // defensive; claimed rows are modified
              if (lane < 36) {
                ulonglong2 v = *(const ulonglong2*)&g_rows[(size_t)r * TW + 2 * lane];
                wx = v.x; wy = v.y;
              }
              loaded = true;
            }
            if (lane < 36) {
              ulonglong2 v; v.x = wx; v.y = wy;
              *(ulonglong2*)&g_rows[(size_t)r * TW + 2 * lane] = v;
            }
            if (lane == 0) lowA[r] = l;
            if (old == INF_I) break;         // no evictee: cascade ends
            int op = old >> EP_BITS;         // op > r (ordering of packed values)
            int oep = old & EP_MASK;
            if (oep == pass) {               // same-pass evictee: store in flight
              if (lane == 0) { int q = atomicAdd(&cnts[nxt], 1); lists[nxt][q] = op; }
              break;
            }
            // ---- adopt evictee: settled row ^ my register row ----
            ull qx = 0, qy = 0;
            if (lane < 36) {
              ulonglong2 v = *(const ulonglong2*)&g_rows[(size_t)op * TW + 2 * lane];
              qx = v.x; qy = v.y;
            }
            wx ^= qx; wy ^= qy;
            r = op; modified = true; loaded = true;
            l = row_low(wx, wy, lane);       // < previous l (strict decrease)
            if (l < 0) break;                // unreachable for uncleared rows
            // do_claim stays true: adopted row claims its fresh low
          } else {
            val = old;                       // lost: owner word in hand
            do_claim = false;
          }
        } else {
          int p = val >> EP_BITS;            // p < r always
          if ((val & EP_MASK) == pass) {     // owner claimed this pass: mid-write
            if (modified && lane < 36) {
              ulonglong2 v; v.x = wx; v.y = wy;
              *(ulonglong2*)&g_rows[(size_t)r * TW + 2 * lane] = v;
            }
            if (lane == 0) { lowA[r] = l; int q = atomicAdd(&cnts[nxt], 1); lists[nxt][q] = r; }
            break;
          }
          ull px = 0, py = 0;
          if (lane < 36) {
            ulonglong2 v = *(const ulonglong2*)&g_rows[(size_t)p * TW + 2 * lane];
            px = v.x; py = v.y;
          }
          if (!loaded) {
            if (lane < 36) {
              ulonglong2 v = *(const ulonglong2*)&g_rows[(size_t)r * TW + 2 * lane];
              wx = v.x; wy = v.y;
            }
            loaded = true;
          }
          wx ^= px; wy ^= py;
          modified = true;
          l = row_low(wx, wy, lane);
          if (l < 0) break;                  // unreachable for uncleared rows
          do_claim = true;
        }
      }
    }
    __syncthreads();
    cnt = cnts[nxt];
    pass++;
  }

  // epilogue: pair (edge rank nE-1-r, tri rank nT-1-l); loss1 = sum - max
  float sum = 0.f, mx = 0.f;
  for (int l = tid; l < nT; l += 1024) {
    int v = spiv[l];
    if (v != INF_I) {
      int r = v >> EP_BITS;
      float len = g_ef[nE - 1 - r] - g_tf[nT - 1 - l];
      sum += len;
      mx = fmaxf(mx, len);
    }
  }
  #pragma unroll
  for (int off = 32; off; off >>= 1) {
    sum += __shfl_xor(sum, off, 64);
    mx = fmaxf(mx, __shfl_xor(mx, off, 64));
  }
  if (lane == 0) { ssum[wave] = sum; smax[wave] = mx; }
  __syncthreads();
  if (tid == 0) {
    float S = 0.f, M = 0.f;
    for (int i = 0; i < 16; ++i) { S += ssum[i]; M = fmaxf(M, smax[i]); }
    out[0] = g_loss0 + S - M;
  }
}

extern "C" void kernel_launch(void* const* d_in, const int* in_sizes, int n_in,
                              void* d_out, int out_size, void* d_ws, size_t ws_size,
                              hipStream_t stream) {
  const float* beta = (const float*)d_in[0];
  const int*   sv   = (const int*)d_in[1];
  const int*   sd   = (const int*)d_in[2];
  const int*   bf   = (const int*)d_in[4];
  float* out = (float*)d_out;

  int nV = in_sizes[0];
  int nS = in_sizes[2];

  k_main1<<<RB_E + RB_T + 1 + RB_C, 256, 0, stream>>>(beta, sv, sd, nV, nS);
  k_scat<<<TBLK + 1, 256, 0, stream>>>(bf, sd, nV, nS);
  k_reduce<<<1, 1024, 0, stream>>>(sd, nV, nS, out);
}

// Round 16
// 170.556 us; speedup vs baseline: 1.1292x; 1.0023x over previous
//
#include <hip/hip_runtime.h>
#include <stdint.h>

// Fixed 8x8x8 grid complex: nV=512, nE=2863, nT=4410, nTet=2058, nS=9843.
// Dim-1 pairs via COHOMOLOGY (coboundary delta_1) + clearing of MST edges:
// rows = edges (reverse filtration order), bits = triangles (reverse order).
// Negative (MST) edges' rows would reduce to zero -> cleared upfront.
#define MAX_E 3072
#define MAX_T 4608
#define MAX_V 1024
#define TW    72     // u64 words per row >= ceil(nT/64); 2 words/lane, lanes 0..35
#define INF_I 0x7fffffff
#define RB_E  12     // edge-rank blocks
#define RB_T  18     // tri-rank blocks
#define RB_C  24     // clear blocks
#define TBLK  18     // scatter blocks = ceil(MAX_T/256)
// spiv packing: value = (row << 14) | epoch. atomicMin orders by row (high
// bits); epoch==current pass marks "claimed this pass, row may be mid-write".
#define EP_BITS  14
#define EP_MASK  0x3FFF
#define EP_DONE  0x3FFF   // settled marker (pass counter capped below it)

typedef unsigned long long ull;

__device__ int   g_erank[MAX_E];             // edge local idx -> rank (f desc, idx asc)
__device__ int   g_eorder[MAX_E];            // rank -> edge local idx
__device__ float g_ef[MAX_E];                // f by edge rank
__device__ int   g_trank[MAX_T];             // tri local idx -> rank
__device__ float g_tf[MAX_T];                // f by tri rank
__device__ __attribute__((aligned(16))) ull g_rows[(size_t)MAX_E * TW];
__device__ int   g_mst[MAX_E];               // edge idx -> 1 if MST (negative) edge
__device__ int   g_clr[MAX_E];               // row rr -> 1 if cleared
__device__ int   g_ilow[MAX_E];              // row rr -> initial low (max bit), -1 if none
__device__ float g_loss0;

// sd is sorted (verts, edges, tris, tets): first index with dim > d.
__device__ __forceinline__ int ub_dim(const int* __restrict__ sd, int nS, int d) {
  int lo = 0, hi = nS;
  while (lo < hi) { int mid = (lo + hi) >> 1; if (sd[mid] <= d) lo = mid + 1; else hi = mid; }
  return lo;
}

// Orderable key: key_j > key_i  <=>  (fj > fi) || (fj == fi && j < i).
__device__ __forceinline__ ull rank_key(float f, int j) {
  unsigned bb = __float_as_uint(f);
  unsigned ord = (bb & 0x80000000u) ? ~bb : (bb | 0x80000000u);
  return ((ull)ord << 32) | (ull)(0xffffffffu - (unsigned)j);
}

// Count keys > ki with 4 independent ds_read_b128 in flight per iteration
// (ILP hides LDS latency: rank blocks run 1 wave/SIMD, no TLP available).
__device__ __forceinline__ int rank_count64(const ull* __restrict__ sk, int n, ull ki) {
  int r = 0, j = 0;
  for (; j + 8 <= n; j += 8) {
    ulonglong2 a = *(const ulonglong2*)(sk + j);
    ulonglong2 b = *(const ulonglong2*)(sk + j + 2);
    ulonglong2 c = *(const ulonglong2*)(sk + j + 4);
    ulonglong2 d = *(const ulonglong2*)(sk + j + 6);
    r += (int)(a.x > ki) + (int)(a.y > ki) + (int)(b.x > ki) + (int)(b.y > ki)
       + (int)(c.x > ki) + (int)(c.y > ki) + (int)(d.x > ki) + (int)(d.y > ki);
  }
  for (; j < n; ++j) r += (int)(sk[j] > ki);
  return r;
}

// Find with path halving. Races with concurrent halving writes are benign
// (every write installs an ancestor; hooks are barrier-separated from finds).
__device__ __forceinline__ int uf_find(int* par, int x) {
  for (;;) {
    int p = par[x];
    if (p == x) return x;
    int gp = par[p];
    if (p != gp) par[x] = gp;
    x = gp;
  }
}

// K1: independent roles — edge ranks | tri ranks | UF (Boruvka) | row clear.
// UF is rank-independent (writes g_mst by edge idx), so all roles overlap.
union SharedK1 {
  struct { alignas(16) ull sk[MAX_T]; } rank;
  struct {
    int par[MAX_V]; ull cand[MAX_V]; int hookTo[MAX_V];
    int eu[MAX_E], ev2[MAX_E];
    float efv[MAX_E];
    unsigned int ekey[MAX_E];
    unsigned short alive[2][MAX_E];
    unsigned char mstf[MAX_E];
  } uf;
};

__global__ void __launch_bounds__(256) k_main1(const float* __restrict__ beta,
                                               const int* __restrict__ sv,
                                               const int* __restrict__ sd,
                                               int nV, int nS) {
  __shared__ SharedK1 sh;
  __shared__ float aS[4], aM[4], aW[4];
  __shared__ int nNext;
  int b = blockIdx.x, tid = threadIdx.x;
  int nE = ub_dim(sd, nS, 1) - nV;

  if (b < RB_E) {
    // ---- edge ranks via u64-key counting ----
    int i = b * 256 + tid;
    float fi = 0.f;
    for (int j = tid; j < nE; j += 256) {     // j==i hit here (j ≡ tid mod 256)
      const int* p = &sv[(size_t)(nV + j) * 4];
      float fj = fminf(beta[p[0]], beta[p[1]]);
      if (j == i) fi = fj;
      sh.rank.sk[j] = rank_key(fj, j);
    }
    __syncthreads();
    if (i >= nE) return;
    int r = rank_count64(sh.rank.sk, nE, sh.rank.sk[i]);
    g_erank[i] = r;
    g_eorder[r] = i;
    g_ef[r] = fi;
    return;
  }
  if (b < RB_E + RB_T) {
    // ---- tri ranks ----
    int nT = ub_dim(sd, nS, 2) - nV - nE;
    int base = nV + nE;
    int i = (b - RB_E) * 256 + tid;
    float fi = 0.f;
    for (int j = tid; j < nT; j += 256) {
      const int* p = &sv[(size_t)(base + j) * 4];
      float fj = fminf(fminf(beta[p[0]], beta[p[1]]), beta[p[2]]);
      if (j == i) fi = fj;
      sh.rank.sk[j] = rank_key(fj, j);
    }
    __syncthreads();
    if (i >= nT) return;
    int r = rank_count64(sh.rank.sk, nT, sh.rank.sk[i]);
    g_trank[i] = r;
    g_tf[r] = fi;
    return;
  }
  if (b > RB_E + RB_T) {
    // ---- clear g_rows + init g_ilow ----
    size_t i = (size_t)(b - RB_E - RB_T - 1) * 256 + tid;
    size_t stride = (size_t)RB_C * 256;
    for (size_t k = i; k < (size_t)MAX_E * TW; k += stride) g_rows[k] = 0ull;
    for (size_t k = i; k < MAX_E; k += stride) g_ilow[k] = -1;
    return;
  }

  // ---- UF role: loss0 = sum_v f(v) - max_v f(v) - W(canonical max ST).
  // Boruvka with STRICT keys (f desc, idx asc) == Kruskal's negative edge set.
  // Path-halving finds, 2 compress sweeps, terminate on empty alive list.
  int lane = tid & 63, wave = tid >> 6;
  int* par = sh.uf.par;
  for (int v = tid; v < nV; v += 256) par[v] = v;
  for (int e = tid; e < nE; e += 256) {
    int u = sv[(size_t)(nV + e) * 4];
    int v = sv[(size_t)(nV + e) * 4 + 1];
    sh.uf.eu[e] = u; sh.uf.ev2[e] = v;
    float fe = fminf(beta[u], beta[v]);
    sh.uf.efv[e] = fe;
    unsigned int bb = __float_as_uint(fe);
    sh.uf.ekey[e] = (bb & 0x80000000u) ? ~bb : (bb | 0x80000000u);  // orderable
    sh.uf.alive[0][e] = (unsigned short)e;
    sh.uf.mstf[e] = 0;
  }
  float s = 0.f, m = -3.0e38f;
  for (int v = tid; v < nV; v += 256) { float fv = beta[v]; s += fv; m = fmaxf(m, fv); }
  float W = 0.f;
  int nAlive = nE, cur = 0;
  __syncthreads();
  for (int phase = 0; phase < 20 && nAlive > 0; ++phase) {
    for (int v = tid; v < nV; v += 256) sh.uf.cand[v] = 0ull;
    if (tid == 0) nNext = 0;
    __syncthreads();
    for (int i0 = 0; i0 < nAlive; i0 += 256) {
      int i = i0 + tid;
      int e = -1;
      bool cross = false;
      int ra = 0, rb = 0;
      if (i < nAlive) {
        e = sh.uf.alive[cur][i];
        ra = uf_find(par, sh.uf.eu[e]);
        rb = uf_find(par, sh.uf.ev2[e]);
        cross = (ra != rb);
      }
      ull mb = __ballot(cross);
      int base = 0;
      if (lane == 0 && mb) base = atomicAdd(&nNext, __popcll(mb));
      base = __shfl(base, 0);
      if (cross) {
        int off = __popcll(mb & ((1ull << lane) - 1ull));
        sh.uf.alive[cur ^ 1][base + off] = (unsigned short)e;
        // key: larger f wins; tie -> SMALLER edge idx wins (canonical order)
        ull key = ((ull)sh.uf.ekey[e] << 32) | (ull)(0xffffffffu - (unsigned)e);
        atomicMax(&sh.uf.cand[ra], key);
        atomicMax(&sh.uf.cand[rb], key);
      }
    }
    __syncthreads();
    for (int v = tid; v < nV; v += 256) {
      int t = -1;
      ull cv = sh.uf.cand[v];
      if (par[v] == v && cv) {
        int e = (int)(0xffffffffu - (unsigned)(cv & 0xffffffffu));
        int ra = uf_find(par, sh.uf.eu[e]);
        int rb = uf_find(par, sh.uf.ev2[e]);
        int other = (ra == v) ? rb : ra;
        if (sh.uf.cand[other] != cv || v < other) t = other;  // break 2-cycles
      }
      sh.uf.hookTo[v] = t;
    }
    __syncthreads();
    for (int v = tid; v < nV; v += 256) {
      int t = sh.uf.hookTo[v];
      if (t >= 0) {
        par[v] = t;
        int e = (int)(0xffffffffu - (unsigned)(sh.uf.cand[v] & 0xffffffffu));
        W += sh.uf.efv[e];
        sh.uf.mstf[e] = 1;                   // negative edge
      }
    }
    __syncthreads();
    for (int it = 0; it < 2; ++it) {
      for (int v = tid; v < nV; v += 256) {
        int p = par[v]; int gp = par[p];
        if (p != gp) par[v] = gp;
      }
      __syncthreads();
    }
    nAlive = nNext;
    cur ^= 1;
    __syncthreads();                          // nNext read-before-reset fence
  }
  __syncthreads();
  // write MST flags once
  for (int e = tid; e < nE; e += 256) g_mst[e] = sh.uf.mstf[e];
  #pragma unroll
  for (int off = 32; off; off >>= 1) {
    s += __shfl_xor(s, off, 64);
    m = fmaxf(m, __shfl_xor(m, off, 64));
    W += __shfl_xor(W, off, 64);
  }
  if (lane == 0) { aS[wave] = s; aM[wave] = m; aW[wave] = W; }
  __syncthreads();
  if (tid == 0) {
    float S = 0.f, M = -3.0e38f, WW = 0.f;
    for (int i = 0; i < 4; ++i) { S += aS[i]; M = fmaxf(M, aM[i]); WW += aW[i]; }
    g_loss0 = S - M - WW;
  }
}

// K2: blocks [0,TBLK) scatter coboundary rows + accumulate each row's initial
// low via atomicMax; block TBLK translates MST flags into cleared-row flags.
__global__ void __launch_bounds__(256) k_scat(const int* __restrict__ bf,
                                              const int* __restrict__ sd,
                                              int nV, int nS) {
  int nE = ub_dim(sd, nS, 1) - nV;
  int tid = threadIdx.x;
  if (blockIdx.x == TBLK) {
    for (int r = tid; r < nE; r += 256)
      g_clr[nE - 1 - r] = g_mst[g_eorder[r]];
    return;
  }
  int nT = ub_dim(sd, nS, 2) - nV - nE;
  int t = blockIdx.x * 256 + tid;
  if (t >= nT) return;
  int lpos = nT - 1 - g_trank[t];
  size_t base = (size_t)2 * nE + (size_t)3 * t;
  ull bit = 1ull << (lpos & 63);
  int word = lpos >> 6;
  for (int j = 0; j < 3; ++j) {
    int e = bf[base + j] - nV;
    int rr = nE - 1 - g_erank[e];
    atomicOr(&g_rows[(size_t)rr * TW + word], bit);
    atomicMax(&g_ilow[rr], lpos);
  }
}

__device__ __forceinline__ int row_low(ull x, ull y, int lane) {
  ull msk = __ballot((x | y) != 0ull);
  int hb = y ? (lane * 128 + 127 - __clzll(y)) : (lane * 128 + 63 - __clzll(x | 1ull));
  return msk ? __shfl(hb, 63 - __clzll(msk)) : -1;
}

// delta_1 reduction. Bulk loop: R15 cascade-collapse (claim-first, adoption).
// SERIAL TAIL (the measured time sink: avg chain concurrency ~1.3 => tail
// dominates): claim-first unified step — atomicMin IS the owner lookup (its
// return value names the pre-claim owner in BOTH win and lose cases, and
// that owner's row is exactly the row to XOR next: lose => reduce through
// owner; win+evict => adopt evictee). No spiv pre-read, no queue restarts,
// no own-row re-reads: ~390 cyc/step vs ~505+ before. Single actor => race-
// free; low strictly decreases per XOR => terminates.
__global__ void __launch_bounds__(1024) k_reduce(const int* __restrict__ sd,
                                                 int nV, int nS,
                                                 float* __restrict__ out) {
  __shared__ int spiv[MAX_T];       // tri position -> (owner row << 14) | epoch
  __shared__ int lowA[MAX_E];
  __shared__ int lists[2][MAX_E];
  __shared__ int tailq[64];
  __shared__ int cnts[2];
  __shared__ int workIdx;
  __shared__ float ssum[16], smax[16];

  int tid = threadIdx.x;
  int lane = tid & 63;
  int wave = tid >> 6;
  int nE = ub_dim(sd, nS, 1) - nV;
  int nT = ub_dim(sd, nS, 2) - nV - nE;

  for (int i = tid; i < nT; i += 1024) spiv[i] = INF_I;
  if (tid == 0) { cnts[0] = 0; cnts[1] = 0; }
  __syncthreads();

  // initial lows from g_ilow (no row reads) + claims (settled: rows untouched)
  for (int r = tid; r < nE; r += 1024) {
    int l = g_clr[r] ? -1 : g_ilow[r];
    lowA[r] = l;
    if (l >= 0) atomicMin(&spiv[l], (r << EP_BITS) | EP_DONE);
  }
  __syncthreads();
  for (int r = tid; r < nE; r += 1024) {
    int l = lowA[r];
    if (l >= 0 && (spiv[l] >> EP_BITS) != r) { int q = atomicAdd(&cnts[0], 1); lists[0][q] = r; }
  }
  __syncthreads();

  int pass = 0;
  int cnt = cnts[0];
  while (cnt > 0 && pass < 16000) {
    int cur = pass & 1, nxt = cur ^ 1;

    if (cnt <= 8) {
      // ---- serial tail: claim-first + adoption, one unified step ----
      if (wave == 0) {
        for (int i = lane; i < cnt; i += 64) tailq[i] = lists[cur][i];
        int head = 0;
        while (head < cnt) {
          int r = tailq[head & 63]; head++;
          int l = lowA[r];                   // row's current low
          ull wx = 0, wy = 0;                // own row loaded ONCE per chain
          if (lane < 36) {
            ulonglong2 v = *(const ulonglong2*)&g_rows[(size_t)r * TW + 2 * lane];
            wx = v.x; wy = v.y;
          }
          for (;;) {
            int myval = (r << EP_BITS) | EP_DONE;
            int old = 0;
            if (lane == 0) old = atomicMin(&spiv[l], myval);
            old = __shfl(old, 0);
            bool won = (old > myval);
            if (won) {
              // publish my row as the settled owner of l (fire-and-forget;
              // only this wave reads it later, vmcnt ordering suffices)
              if (lane < 36) {
                ulonglong2 v; v.x = wx; v.y = wy;
                *(ulonglong2*)&g_rows[(size_t)r * TW + 2 * lane] = v;
              }
              if (lane == 0) lowA[r] = l;
              if (old == INF_I) break;       // no evictee: chain ends
            }
            // unified XOR step: old names the pre-claim owner in both cases
            int p = old >> EP_BITS;
            ull px = 0, py = 0;
            if (lane < 36) {
              ulonglong2 v = *(const ulonglong2*)&g_rows[(size_t)p * TW + 2 * lane];
              px = v.x; py = v.y;
            }
            wx ^= px; wy ^= py;
            if (won) r = p;                  // adopt evictee's identity
            l = row_low(wx, wy, lane);       // strictly decreases (lows cancel)
            if (l < 0) break;                // unreachable for uncleared rows
          }
        }
      }
      __syncthreads();
      break;
    }

    if (tid == 0) { cnts[nxt] = 0; workIdx = 0; }
    __syncthreads();
    for (;;) {
      int idx = 0;
      if (lane == 0) idx = atomicAdd(&workIdx, 1);
      idx = __shfl(idx, 0);
      if (idx >= cnt) break;
      int r = lists[cur][idx];
      int l = lowA[r];                       // >= 0 for every listed row
      ull wx = 0, wy = 0;
      bool loaded = false, modified = false;
      bool do_claim = true;                  // listed rows' first claim provably
      int val = 0;                           // loses and fetches the owner word
      for (;;) {
        if (do_claim) {
          int myval = (r << EP_BITS) | pass;
          int old = 0;
          if (lane == 0) old = atomicMin(&spiv[l], myval);
          old = __shfl(old, 0);
          if (old > myval) {
            // ---- claimed: publish row now (readers defer on epoch==pass) ----
            if (!loaded) {                   // defensive; claimed rows are modified
              if (lane < 36) {
                ulonglong2 v = *(const ulonglong2*)&g_rows[(size_t)r * TW + 2 * lane];
                wx = v.x; wy = v.y;
              }
              loaded = true;
            }
            if (lane < 36) {
              ulonglong2 v; v.x = wx; v.y = wy;
              *(ulonglong2*)&g_rows[(size_t)r * TW + 2 * lane] = v;
            }
            if (lane == 0) lowA[r] = l;
            if (old == INF_I) break;         // no evictee: cascade ends
            int op = old >> EP_BITS;         // op > r (ordering of packed values)
            int oep = old & EP_MASK;
            if (oep == pass) {               // same-pass evictee: store in flight
              if (lane == 0) { int q = atomicAdd(&cnts[nxt], 1); lists[nxt][q] = op; }
              break;
            }
            // ---- adopt evictee: settled row ^ my register row ----
            ull qx = 0, qy = 0;
            if (lane < 36) {
              ulonglong2 v = *(const ulonglong2*)&g_rows[(size_t)op * TW + 2 * lane];
              qx = v.x; qy = v.y;
            }
            wx ^= qx; wy ^= qy;
            r = op; modified = true; loaded = true;
            l = row_low(wx, wy, lane);       // < previous l (strict decrease)
            if (l < 0) break;                // unreachable for uncleared rows
            // do_claim stays true: adopted row claims its fresh low
          } else {
            val = old;                       // lost: owner word in hand
            do_claim = false;
          }
        } else {
          int p = val >> EP_BITS;            // p < r always
          if ((val & EP_MASK) == pass) {     // owner claimed this pass: mid-write
            if (modified && lane < 36) {
              ulonglong2 v; v.x = wx; v.y = wy;
              *(ulonglong2*)&g_rows[(size_t)r * TW + 2 * lane] = v;
            }
            if (lane == 0) { lowA[r] = l; int q = atomicAdd(&cnts[nxt], 1); lists[nxt][q] = r; }
            break;
          }
          ull px = 0, py = 0;
          if (lane < 36) {
            ulonglong2 v = *(const ulonglong2*)&g_rows[(size_t)p * TW + 2 * lane];
            px = v.x; py = v.y;
          }
          if (!loaded) {
            if (lane < 36) {
              ulonglong2 v = *(const ulonglong2*)&g_rows[(size_t)r * TW + 2 * lane];
              wx = v.x; wy = v.y;
            }
            loaded = true;
          }
          wx ^= px; wy ^= py;
          modified = true;
          l = row_low(wx, wy, lane);
          if (l < 0) break;                  // unreachable for uncleared rows
          do_claim = true;
        }
      }
    }
    __syncthreads();
    cnt = cnts[nxt];
    pass++;
  }

  // epilogue: pair (edge rank nE-1-r, tri rank nT-1-l); loss1 = sum - max
  float sum = 0.f, mx = 0.f;
  for (int l = tid; l < nT; l += 1024) {
    int v = spiv[l];
    if (v != INF_I) {
      int r = v >> EP_BITS;
      float len = g_ef[nE - 1 - r] - g_tf[nT - 1 - l];
      sum += len;
      mx = fmaxf(mx, len);
    }
  }
  #pragma unroll
  for (int off = 32; off; off >>= 1) {
    sum += __shfl_xor(sum, off, 64);
    mx = fmaxf(mx, __shfl_xor(mx, off, 64));
  }
  if (lane == 0) { ssum[wave] = sum; smax[wave] = mx; }
  __syncthreads();
  if (tid == 0) {
    float S = 0.f, M = 0.f;
    for (int i = 0; i < 16; ++i) { S += ssum[i]; M = fmaxf(M, smax[i]); }
    out[0] = g_loss0 + S - M;
  }
}

extern "C" void kernel_launch(void* const* d_in, const int* in_sizes, int n_in,
                              void* d_out, int out_size, void* d_ws, size_t ws_size,
                              hipStream_t stream) {
  const float* beta = (const float*)d_in[0];
  const int*   sv   = (const int*)d_in[1];
  const int*   sd   = (const int*)d_in[2];
  const int*   bf   = (const int*)d_in[4];
  float* out = (float*)d_out;

  int nV = in_sizes[0];
  int nS = in_sizes[2];

  k_main1<<<RB_E + RB_T + 1 + RB_C, 256, 0, stream>>>(beta, sv, sd, nV, nS);
  k_scat<<<TBLK + 1, 256, 0, stream>>>(bf, sd, nV, nS);
  k_reduce<<<1, 1024, 0, stream>>>(sd, nV, nS, out);
}